// Round 6
// baseline (275.743 us; speedup 1.0000x reference)
//
#include <hip/hip_runtime.h>
#include <hip/hip_bf16.h>
#include <cstddef>
#include <cstdint>

// Problem constants (fixed by reference)
#define BATCH   2
#define S_LEN   2048
#define D_MODEL 1024
#define NH      16
#define HD      64
#define MAXD    1024

// logits = scores*(1/sqrt(64)) + (scores + rel_bias)*64^-0.25
//        = scores*0.47855339 + rel_bias*0.35355339
#define SCORE_SCALE 0.47855339059327373f
#define BIAS_SCALE  0.35355339059327373f
// fixed softmax shift (|logit| << 8): softmax is shift-invariant; folded into bias table
#define FIXM 8.0f
#define LOG2E 1.4426950408889634f

typedef __attribute__((ext_vector_type(8))) short bf16x8;
typedef __attribute__((ext_vector_type(4))) float f32x4;

static __device__ __forceinline__ unsigned short f2bf(float f) {
    __hip_bfloat16 h = __float2bfloat16(f);
    return *reinterpret_cast<unsigned short*>(&h);
}
static __device__ __forceinline__ float bf2f(unsigned short u) {
    union { unsigned int i; float f; } c;
    c.i = ((unsigned int)u) << 16;
    return c.f;
}

#define GLDS(gp, lp) __builtin_amdgcn_global_load_lds( \
    (const __attribute__((address_space(1))) void*)(gp), \
    (__attribute__((address_space(3))) void*)(lp), 16, 0, 0)

// ---------------------------------------------------------------------------
// fp32 -> bf16 elementwise convert (x).
// ---------------------------------------------------------------------------
__global__ __launch_bounds__(256) void cvt_bf16(
    const float* __restrict__ src, unsigned short* __restrict__ dst)
{
    const size_t i = ((size_t)blockIdx.x * 256 + threadIdx.x) * 8;
    const float4 a = *(const float4*)(src + i);
    const float4 b = *(const float4*)(src + i + 4);
    unsigned short u[8] = {f2bf(a.x), f2bf(a.y), f2bf(a.z), f2bf(a.w),
                           f2bf(b.x), f2bf(b.y), f2bf(b.z), f2bf(b.w)};
    *(uint4*)(dst + i) = *(const uint4*)u;
}

// ---------------------------------------------------------------------------
// All weight transposes+converts in one launch. z=0,1,2 -> Wq/Wk/Wv into the
// concatenated Wqkvt [3072][1024]; z=3 -> Wo split-precision hi/lo.
// ---------------------------------------------------------------------------
__global__ __launch_bounds__(256) void wt_convert_all(
    const float* __restrict__ Wq, const float* __restrict__ Wk,
    const float* __restrict__ Wv, const float* __restrict__ Wo,
    unsigned short* __restrict__ Wqkvt, unsigned short* __restrict__ Wot_hi,
    unsigned short* __restrict__ Wot_lo)
{
    const int z = blockIdx.z;
    const float* W = (z == 0) ? Wq : (z == 1) ? Wk : (z == 2) ? Wv : Wo;
    unsigned short* hi = (z < 3) ? Wqkvt + (size_t)z * 1024 * 1024 : Wot_hi;
    unsigned short* lo = (z == 3) ? Wot_lo : nullptr;

    __shared__ float t[32][33];
    const int bx = blockIdx.x * 32, by = blockIdx.y * 32;
    const int tx = threadIdx.x & 31, ty = threadIdx.x >> 5;  // ty 0..7
    #pragma unroll
    for (int i = 0; i < 4; i++)
        t[ty + 8 * i][tx] = W[(size_t)(by + ty + 8 * i) * 1024 + bx + tx];
    __syncthreads();
    #pragma unroll
    for (int i = 0; i < 4; i++) {
        const float v = t[tx][ty + 8 * i];       // = W[by+tx][bx+ty+8i]
        const unsigned short h = f2bf(v);
        const size_t o = (size_t)(bx + ty + 8 * i) * 1024 + by + tx;
        hi[o] = h;
        if (lo) lo[o] = f2bf(v - bf2f(h));
    }
}

// ---------------------------------------------------------------------------
// bf16 MFMA GEMM: C[M,N] = A[M,K] @ Bt[N,K]^T (+bias).
// 128x128 tile, BK=32, 256 threads = 4 waves (2x2), 4x4 16x16x32 frags/wave.
// MODE 2: fp32 C [M,N] (final projection).
// MODE 3: fused QKV epilogue. Cout is base of {Qb | Kb | VTb} each 4Mi bf16;
//         col region 0->Q [B,S,D], 1->K [B,S,D], 2->V^T [B,H,HD,S] (packed).
// SPLITB: accumulate A@Bt + A@Bt2 (split-precision weight).
// ---------------------------------------------------------------------------
#define GBM 128
#define GBN 128
#define GBK 32

template<int MODE, bool SPLITB>
__global__ __launch_bounds__(256) void gemm_mfma(
    const unsigned short* __restrict__ A, const unsigned short* __restrict__ Bt,
    const unsigned short* __restrict__ Bt2, const float* __restrict__ bias,
    const float* __restrict__ bias2, void* __restrict__ Cout,
    int M, int N, int K)
{
    __shared__ __align__(16) unsigned short As[GBM][GBK];
    __shared__ __align__(16) unsigned short Bs[SPLITB ? 2 : 1][GBN][GBK];

    const int tid = threadIdx.x;
    const int wave = tid >> 6, lane = tid & 63;
    const int quad = lane >> 4, cl = lane & 15;
    const int wm = (wave & 1) * 64, wn = (wave >> 1) * 64;
    const int bm = blockIdx.y * GBM, bn = blockIdx.x * GBN;

    const int sr = wave * 32 + (lane >> 2);   // staging row (second instr: +16)
    const int sc = (lane & 3) * 8;            // 16 B chunk
    const unsigned short* aS0 = A   + (size_t)(bm + sr) * K + sc;
    const unsigned short* aS1 = aS0 + (size_t)16 * K;
    const unsigned short* bS0 = Bt  + (size_t)(bn + sr) * K + sc;
    const unsigned short* bS1 = bS0 + (size_t)16 * K;
    const unsigned short* cS0 = SPLITB ? Bt2 + (size_t)(bn + sr) * K + sc : nullptr;
    const unsigned short* cS1 = SPLITB ? cS0 + (size_t)16 * K : nullptr;
    unsigned short* aD0 = &As[wave * 32][0];
    unsigned short* aD1 = &As[wave * 32 + 16][0];
    unsigned short* bD0 = &Bs[0][wave * 32][0];
    unsigned short* bD1 = &Bs[0][wave * 32 + 16][0];
    unsigned short* cD0 = SPLITB ? &Bs[1][wave * 32][0] : nullptr;
    unsigned short* cD1 = SPLITB ? &Bs[1][wave * 32 + 16][0] : nullptr;

    f32x4 acc[4][4];
    #pragma unroll
    for (int mi = 0; mi < 4; mi++)
        #pragma unroll
        for (int ni = 0; ni < 4; ni++)
            #pragma unroll
            for (int r = 0; r < 4; r++) acc[mi][ni][r] = 0.f;

    for (int k0 = 0; k0 < K; k0 += GBK) {
        __syncthreads();
        GLDS(aS0, aD0); GLDS(aS1, aD1);
        GLDS(bS0, bD0); GLDS(bS1, bD1);
        if (SPLITB) { GLDS(cS0, cD0); GLDS(cS1, cD1); }
        aS0 += GBK; aS1 += GBK; bS0 += GBK; bS1 += GBK;
        if (SPLITB) { cS0 += GBK; cS1 += GBK; }
        __syncthreads();  // barrier drains vmcnt -> glds data visible

        bf16x8 af[4], bf[4];
        #pragma unroll
        for (int mi = 0; mi < 4; mi++)
            af[mi] = *(const bf16x8*)&As[wm + mi * 16 + cl][quad * 8];
        #pragma unroll
        for (int ni = 0; ni < 4; ni++)
            bf[ni] = *(const bf16x8*)&Bs[0][wn + ni * 16 + cl][quad * 8];
        #pragma unroll
        for (int mi = 0; mi < 4; mi++)
            #pragma unroll
            for (int ni = 0; ni < 4; ni++)
                acc[mi][ni] = __builtin_amdgcn_mfma_f32_16x16x32_bf16(
                    af[mi], bf[ni], acc[mi][ni], 0, 0, 0);
        if (SPLITB) {
            bf16x8 bf2[4];
            #pragma unroll
            for (int ni = 0; ni < 4; ni++)
                bf2[ni] = *(const bf16x8*)&Bs[1][wn + ni * 16 + cl][quad * 8];
            #pragma unroll
            for (int mi = 0; mi < 4; mi++)
                #pragma unroll
                for (int ni = 0; ni < 4; ni++)
                    acc[mi][ni] = __builtin_amdgcn_mfma_f32_16x16x32_bf16(
                        af[mi], bf2[ni], acc[mi][ni], 0, 0, 0);
        }
    }

    // epilogue; C/D layout: m = quad*4+r, n = cl
    #pragma unroll
    for (int ni = 0; ni < 4; ni++) {
        const int coln = bn + wn + ni * 16 + cl;
        float bs = 0.f;
        int region = 0, c = coln;
        if (MODE == 3) {
            region = coln >> 10; c = coln & 1023;
            bs = (region == 0) ? bias[c] : (region == 2) ? bias2[c] : 0.f;
        } else {
            bs = bias ? bias[coln] : 0.f;
        }
        #pragma unroll
        for (int mi = 0; mi < 4; mi++) {
            const int row0 = bm + wm + mi * 16 + quad * 4;
            if (MODE == 3 && region == 2) {
                // V^T store: pack 4 consecutive s (r=0..3) into one b64
                const int hh = c >> 6, d = c & 63;
                const int bb = row0 >> 11, s0 = row0 & 2047;
                unsigned short u[4];
                #pragma unroll
                for (int r = 0; r < 4; r++) u[r] = f2bf(acc[mi][ni][r] + bs);
                unsigned short* dst = (unsigned short*)Cout + (size_t)8 * 1024 * 1024
                    + (((size_t)bb * NH + hh) * HD + d) * S_LEN + s0;
                *(uint2*)dst = *(const uint2*)u;
            } else {
                #pragma unroll
                for (int r = 0; r < 4; r++) {
                    const int row = row0 + r;
                    const float v = acc[mi][ni][r] + bs;
                    if (MODE == 3) {
                        unsigned short* dst = (unsigned short*)Cout
                            + (size_t)region * 4 * 1024 * 1024;
                        dst[(size_t)row * 1024 + c] = f2bf(v);
                    } else {
                        ((float*)Cout)[(size_t)row * N + coln] = v;
                    }
                }
            }
        }
    }
}

// ---------------------------------------------------------------------------
// MFMA flash attention, transposed-score formulation, 32 q-rows per wave.
// Q,K: bf16 [B,S,D]; VT: bf16 [B,H,HD,S]; O: bf16 [B,S,D].
// Grid (S/128, NH, B), 256 thr = 4 waves; each wave owns 32 q (2 groups of 16).
// S^T = mfma(kf, qf[qg]): C[key=nb*16+quad*4+r][q=qg*16+col] -> packed b64
// P-writes, one lsum scalar per (lane,qg). K/V frags read once, shared by qg.
// Register prefetch of next K/V/bias tile hides VMEM latency under compute.
// Fixed-shift softmax (FIXM and log2e folded into bias table), exp2 path.
// ---------------------------------------------------------------------------
#define TQB 128
#define TKB 64
#define KP  72   // padded stride (bf16): 144 B rows -> benign conflict pattern

__global__ __launch_bounds__(256) void attn_mfma(
    const unsigned short* __restrict__ Q, const unsigned short* __restrict__ K,
    const unsigned short* __restrict__ VT, const float* __restrict__ pos_bias,
    unsigned short* __restrict__ O)
{
    const int qt = blockIdx.x, h = blockIdx.y, b = blockIdx.z;
    const int tid  = threadIdx.x;
    const int wave = tid >> 6, lane = tid & 63;
    const int quad = lane >> 4, col = lane & 15;
    const int qbase = qt * TQB;
    const int qw = qbase + wave * 32;

    __shared__ __align__(16) unsigned short Ks[TKB][KP];    // [key][d]
    __shared__ __align__(16) unsigned short Vt[HD][KP];     // [d][key]
    __shared__ __align__(16) unsigned short Ps[4][32][KP];  // per-wave P [q][key]
    __shared__ float bias_s[192];

    // Q fragments: qf[qg][kk], A/B-layout n=col, k=kk*32+quad*8
    bf16x8 qf[2][2];
    #pragma unroll
    for (int qg = 0; qg < 2; qg++) {
        const unsigned short* qp =
            &Q[((size_t)(b * S_LEN) + qw + qg * 16 + col) * D_MODEL + h * HD + quad * 8];
        qf[qg][0] = *(const bf16x8*)qp;
        qf[qg][1] = *(const bf16x8*)(qp + 32);
    }

    f32x4 accO[2][4];     // [qg][nb]  O[q=quad*4+r (+qg*16)][d=nb*16+col]
    float lsum[2] = {0.f, 0.f};
    #pragma unroll
    for (int qg = 0; qg < 2; qg++)
        #pragma unroll
        for (int nb = 0; nb < 4; nb++)
            #pragma unroll
            for (int r = 0; r < 4; r++) accO[qg][nb][r] = 0.f;

    // staging maps (256 threads): K rows [key][d], V^T rows [d][key]
    const int skey = tid & 63;            // K row
    const int sd   = (tid >> 6) * 16;     // K elem offset (2 uint4)
    const int vdr  = tid >> 2;            // V^T d-row (0..63)
    const int vco  = (tid & 3) * 16;      // V^T key offset (2 uint4)
    const size_t vbase = ((size_t)(b * NH + h) * HD) * S_LEN;
    const size_t krow  = ((size_t)(b * S_LEN) + skey) * D_MODEL + h * HD + sd;

    // prefetch tile 0
    uint4 kpre[2], vpre[2];
    float bpre = 0.f;
    kpre[0] = *(const uint4*)&K[krow];
    kpre[1] = *(const uint4*)&K[krow + 8];
    vpre[0] = *(const uint4*)&VT[vbase + (size_t)vdr * S_LEN + vco];
    vpre[1] = *(const uint4*)&VT[vbase + (size_t)vdr * S_LEN + vco + 8];
    if (tid < 191) {
        int rel = qbase + tid - 63;
        rel = min(max(rel, -(MAXD - 1)), MAXD - 1);
        bpre = (BIAS_SCALE * pos_bias[(size_t)(rel + MAXD - 1) * NH + h] - FIXM) * LOG2E;
    }

    const float SC2 = SCORE_SCALE * LOG2E;
    const int tb00 = wave * 32 + col + 63 - quad * 4;  // bias idx base, qg=0

    for (int kb = 0; kb < S_LEN; kb += TKB) {
        // commit prefetched tile to LDS
        *(uint4*)&Ks[skey][sd]     = kpre[0];
        *(uint4*)&Ks[skey][sd + 8] = kpre[1];
        *(uint4*)&Vt[vdr][vco]     = vpre[0];
        *(uint4*)&Vt[vdr][vco + 8] = vpre[1];
        if (tid < 191) bias_s[tid] = bpre;
        __syncthreads();

        // issue next tile's global loads (latency hidden under compute)
        if (kb + TKB < S_LEN) {
            const size_t krow2 = krow + (size_t)(kb + TKB) * D_MODEL;
            kpre[0] = *(const uint4*)&K[krow2];
            kpre[1] = *(const uint4*)&K[krow2 + 8];
            vpre[0] = *(const uint4*)&VT[vbase + (size_t)vdr * S_LEN + kb + TKB + vco];
            vpre[1] = *(const uint4*)&VT[vbase + (size_t)vdr * S_LEN + kb + TKB + vco + 8];
            if (tid < 191) {
                int rel = qbase - (kb + TKB) + tid - 63;
                rel = min(max(rel, -(MAXD - 1)), MAXD - 1);
                bpre = (BIAS_SCALE * pos_bias[(size_t)(rel + MAXD - 1) * NH + h] - FIXM) * LOG2E;
            }
        }

        // K fragments once, shared across both q-groups
        bf16x8 kf[2][4];
        #pragma unroll
        for (int kk = 0; kk < 2; kk++)
            #pragma unroll
            for (int nb = 0; nb < 4; nb++)
                kf[kk][nb] = *(const bf16x8*)&Ks[nb * 16 + col][kk * 32 + quad * 8];

        #pragma unroll
        for (int qg = 0; qg < 2; qg++) {
            // S^T: C[key = nb*16 + quad*4 + r][q = qg*16 + col]
            f32x4 accS[4];
            #pragma unroll
            for (int nb = 0; nb < 4; nb++)
                #pragma unroll
                for (int r = 0; r < 4; r++) accS[nb][r] = 0.f;
            #pragma unroll
            for (int kk = 0; kk < 2; kk++)
                #pragma unroll
                for (int nb = 0; nb < 4; nb++)
                    accS[nb] = __builtin_amdgcn_mfma_f32_16x16x32_bf16(
                        kf[kk][nb], qf[qg][kk], accS[nb], 0, 0, 0);

            // p = exp2(score*SC2 + bias2[q-k]); packed b64 P-writes
            const int tb0 = tb00 + qg * 16;
            #pragma unroll
            for (int nb = 0; nb < 4; nb++) {
                const int tb = tb0 - nb * 16;
                float p[4];
                #pragma unroll
                for (int r = 0; r < 4; r++) {
                    p[r] = __builtin_amdgcn_exp2f(fmaf(accS[nb][r], SC2, bias_s[tb - r]));
                    lsum[qg] += p[r];
                }
                const __hip_bfloat162 h0 = __float22bfloat162_rn(make_float2(p[0], p[1]));
                const __hip_bfloat162 h1 = __float22bfloat162_rn(make_float2(p[2], p[3]));
                uint2 w;
                w.x = *(const unsigned int*)&h0;
                w.y = *(const unsigned int*)&h1;
                *(uint2*)&Ps[wave][qg * 16 + col][nb * 16 + quad * 4] = w;
            }
        }

        // PV: O[qg][q=quad*4+r][d=nb*16+col] += P[q][key] * V^T[d][key]
        #pragma unroll
        for (int kk = 0; kk < 2; kk++) {
            bf16x8 vf[4];
            #pragma unroll
            for (int nb = 0; nb < 4; nb++)
                vf[nb] = *(const bf16x8*)&Vt[nb * 16 + col][kk * 32 + quad * 8];
            #pragma unroll
            for (int qg = 0; qg < 2; qg++) {
                const bf16x8 af = *(const bf16x8*)&Ps[wave][qg * 16 + col][kk * 32 + quad * 8];
                #pragma unroll
                for (int nb = 0; nb < 4; nb++)
                    accO[qg][nb] = __builtin_amdgcn_mfma_f32_16x16x32_bf16(
                        af, vf[nb], accO[qg][nb], 0, 0, 0);
            }
        }
        __syncthreads();  // all LDS reads done before next tile's commit
    }

    // reduce l per q-group (lanes col, col+16, col+32, col+48 share q), store
    #pragma unroll
    for (int qg = 0; qg < 2; qg++) {
        float l = lsum[qg];
        l += __shfl_xor(l, 16);
        l += __shfl_xor(l, 32);
        #pragma unroll
        for (int r = 0; r < 4; r++) {
            const float inv = 1.0f / __shfl(l, quad * 4 + r);
            const size_t row = (size_t)(b * S_LEN) + qw + qg * 16 + quad * 4 + r;
            #pragma unroll
            for (int nb = 0; nb < 4; nb++)
                O[row * D_MODEL + h * HD + nb * 16 + col] = f2bf(accO[qg][nb][r] * inv);
        }
    }
}

// ---------------------------------------------------------------------------
extern "C" void kernel_launch(void* const* d_in, const int* in_sizes, int n_in,
                              void* d_out, int out_size, void* d_ws, size_t ws_size,
                              hipStream_t stream)
{
    const float* x        = (const float*)d_in[0];
    const float* Wq       = (const float*)d_in[1];
    const float* bq       = (const float*)d_in[2];
    const float* Wk       = (const float*)d_in[3];
    const float* Wv       = (const float*)d_in[4];
    const float* bv       = (const float*)d_in[5];
    const float* Wo       = (const float*)d_in[6];
    const float* bo       = (const float*)d_in[7];
    const float* pos_bias = (const float*)d_in[8];
    float* out = (float*)d_out;

    const size_t ELEMS  = (size_t)BATCH * S_LEN * D_MODEL;  // 4 Mi
    const size_t WELEMS = (size_t)D_MODEL * D_MODEL;        // 1 Mi
    unsigned short* xb     = (unsigned short*)d_ws;
    unsigned short* Wqkvt  = xb + ELEMS;                    // [3072][1024]
    unsigned short* Wot_hi = Wqkvt + 3 * WELEMS;
    unsigned short* Wot_lo = Wot_hi + WELEMS;
    unsigned short* QKV    = Wot_lo + WELEMS;               // Qb | Kb | VTb
    unsigned short* Qb     = QKV;
    unsigned short* Kb     = Qb + ELEMS;
    unsigned short* VTb    = Kb + ELEMS;                    // [B,H,HD,S]
    unsigned short* Ab     = VTb + ELEMS;                   // attn out bf16 [B,S,D]

    const int M = BATCH * S_LEN;  // 4096

    cvt_bf16<<<ELEMS / (256 * 8), 256, 0, stream>>>(x, xb);
    wt_convert_all<<<dim3(32, 32, 4), 256, 0, stream>>>(
        Wq, Wk, Wv, Wo, Wqkvt, Wot_hi, Wot_lo);

    // fused QKV projection: N = 3072
    gemm_mfma<3, false><<<dim3(3072 / GBN, M / GBM), 256, 0, stream>>>(
        xb, Wqkvt, nullptr, bq, bv, QKV, M, 3072, D_MODEL);

    attn_mfma<<<dim3(S_LEN / TQB, NH, BATCH), 256, 0, stream>>>(Qb, Kb, VTb, pos_bias, Ab);

    gemm_mfma<2, true><<<dim3(D_MODEL / GBN, M / GBM), 256, 0, stream>>>(
        Ab, Wot_hi, Wot_lo, bo, nullptr, out, M, D_MODEL, D_MODEL);
}

// Round 7
// 223.694 us; speedup vs baseline: 1.2327x; 1.2327x over previous
//
#include <hip/hip_runtime.h>
#include <hip/hip_bf16.h>
#include <cstddef>
#include <cstdint>

// Problem constants (fixed by reference)
#define BATCH   2
#define S_LEN   2048
#define D_MODEL 1024
#define NH      16
#define HD      64
#define MAXD    1024

// logits = scores*(1/sqrt(64)) + (scores + rel_bias)*64^-0.25
//        = scores*0.47855339 + rel_bias*0.35355339
#define SCORE_SCALE 0.47855339059327373f
#define BIAS_SCALE  0.35355339059327373f
#define FIXM 8.0f
#define LOG2E 1.4426950408889634f

typedef __attribute__((ext_vector_type(8))) short bf16x8;
typedef __attribute__((ext_vector_type(4))) float f32x4;

static __device__ __forceinline__ unsigned short f2bf(float f) {
    __hip_bfloat16 h = __float2bfloat16(f);
    return *reinterpret_cast<unsigned short*>(&h);
}
static __device__ __forceinline__ float bf2f(unsigned short u) {
    union { unsigned int i; float f; } c;
    c.i = ((unsigned int)u) << 16;
    return c.f;
}

#define GLDS(gp, lp) __builtin_amdgcn_global_load_lds( \
    (const __attribute__((address_space(1))) void*)(gp), \
    (__attribute__((address_space(3))) void*)(lp), 16, 0, 0)

// ---------------------------------------------------------------------------
// prep: one launch for (a) x fp32->bf16, (b) 4 weight transpose+converts,
// (c) per-head bias table pb_t[h][rel+2047] with clamp/scales/log2e folded.
// Grid: 2048 (cvt) + 4096 (wt, 4 z-slices of 32x32) + 64 (pb) = 6208 blocks.
// ---------------------------------------------------------------------------
__global__ __launch_bounds__(256) void prep(
    const float* __restrict__ x,
    const float* __restrict__ Wq, const float* __restrict__ Wk,
    const float* __restrict__ Wv, const float* __restrict__ Wo,
    const float* __restrict__ pos_bias,
    unsigned short* __restrict__ xb, unsigned short* __restrict__ Wqkvt,
    unsigned short* __restrict__ Wot_hi, unsigned short* __restrict__ Wot_lo,
    float* __restrict__ pb_t)
{
    __shared__ float t[32][33];
    const int bx = blockIdx.x, tid = threadIdx.x;

    if (bx < 2048) {                       // ---- x convert
        const size_t i = ((size_t)bx * 256 + tid) * 8;
        const float4 a = *(const float4*)(x + i);
        const float4 b = *(const float4*)(x + i + 4);
        unsigned short u[8] = {f2bf(a.x), f2bf(a.y), f2bf(a.z), f2bf(a.w),
                               f2bf(b.x), f2bf(b.y), f2bf(b.z), f2bf(b.w)};
        *(uint4*)(xb + i) = *(const uint4*)u;
    } else if (bx < 6144) {                // ---- weight transpose+convert
        const int bx2 = bx - 2048;
        const int z = bx2 >> 10, inner = bx2 & 1023;
        const int gx = inner & 31, gy = inner >> 5;
        const float* W = (z == 0) ? Wq : (z == 1) ? Wk : (z == 2) ? Wv : Wo;
        unsigned short* hi = (z < 3) ? Wqkvt + (size_t)z * 1024 * 1024 : Wot_hi;
        unsigned short* lo = (z == 3) ? Wot_lo : nullptr;
        const int bxx = gx * 32, byy = gy * 32;
        const int tx = tid & 31, ty = tid >> 5;
        #pragma unroll
        for (int i = 0; i < 4; i++)
            t[ty + 8 * i][tx] = W[(size_t)(byy + ty + 8 * i) * 1024 + bxx + tx];
        __syncthreads();
        #pragma unroll
        for (int i = 0; i < 4; i++) {
            const float v = t[tx][ty + 8 * i];
            const unsigned short hh = f2bf(v);
            const size_t o = (size_t)(bxx + ty + 8 * i) * 1024 + byy + tx;
            hi[o] = hh;
            if (lo) lo[o] = f2bf(v - bf2f(hh));
        }
    } else {                               // ---- bias table, 16 heads x 4096
        const int o0 = (bx - 6144) * 1024 + tid * 4;
        float v[4];
        #pragma unroll
        for (int j = 0; j < 4; j++) {
            const int o = o0 + j;
            const int hh = o >> 12, ii = o & 4095;
            int rel = ii - 2047;
            rel = min(max(rel, -(MAXD - 1)), MAXD - 1);
            v[j] = (BIAS_SCALE * pos_bias[(size_t)(rel + MAXD - 1) * NH + hh] - FIXM) * LOG2E;
        }
        *(float4*)&pb_t[o0] = *(const float4*)v;
    }
}

// ---------------------------------------------------------------------------
// Fused QKV GEMM: C[4096,3072] = xb @ Wqkvt^T. 128x128 tile, BK=32, m97-style.
// Col region 0->Q [B,S,D] (+bq), 1->K [B,S,D], 2->V^T [B,H,HD,S] (+bv, packed).
// ---------------------------------------------------------------------------
#define GBM 128
#define GBN 128
#define GBK 32

__global__ __launch_bounds__(256) void gemm_qkv(
    const unsigned short* __restrict__ A, const unsigned short* __restrict__ Bt,
    const float* __restrict__ bq, const float* __restrict__ bv,
    unsigned short* __restrict__ Cout)
{
    const int M = 4096, N = 3072, K = 1024;
    __shared__ __align__(16) unsigned short As[GBM][GBK];
    __shared__ __align__(16) unsigned short Bs[GBN][GBK];

    const int tid = threadIdx.x;
    const int wave = tid >> 6, lane = tid & 63;
    const int quad = lane >> 4, cl = lane & 15;
    const int wm = (wave & 1) * 64, wn = (wave >> 1) * 64;
    const int bm = blockIdx.y * GBM, bn = blockIdx.x * GBN;

    const int sr = wave * 32 + (lane >> 2);
    const int sc = (lane & 3) * 8;
    const unsigned short* aS0 = A  + (size_t)(bm + sr) * K + sc;
    const unsigned short* aS1 = aS0 + (size_t)16 * K;
    const unsigned short* bS0 = Bt + (size_t)(bn + sr) * K + sc;
    const unsigned short* bS1 = bS0 + (size_t)16 * K;
    unsigned short* aD0 = &As[wave * 32][0];
    unsigned short* aD1 = &As[wave * 32 + 16][0];
    unsigned short* bD0 = &Bs[wave * 32][0];
    unsigned short* bD1 = &Bs[wave * 32 + 16][0];

    f32x4 acc[4][4];
    #pragma unroll
    for (int mi = 0; mi < 4; mi++)
        #pragma unroll
        for (int ni = 0; ni < 4; ni++)
            #pragma unroll
            for (int r = 0; r < 4; r++) acc[mi][ni][r] = 0.f;

    for (int k0 = 0; k0 < K; k0 += GBK) {
        __syncthreads();
        GLDS(aS0, aD0); GLDS(aS1, aD1);
        GLDS(bS0, bD0); GLDS(bS1, bD1);
        aS0 += GBK; aS1 += GBK; bS0 += GBK; bS1 += GBK;
        __syncthreads();

        bf16x8 af[4], bf[4];
        #pragma unroll
        for (int mi = 0; mi < 4; mi++)
            af[mi] = *(const bf16x8*)&As[wm + mi * 16 + cl][quad * 8];
        #pragma unroll
        for (int ni = 0; ni < 4; ni++)
            bf[ni] = *(const bf16x8*)&Bs[wn + ni * 16 + cl][quad * 8];
        #pragma unroll
        for (int mi = 0; mi < 4; mi++)
            #pragma unroll
            for (int ni = 0; ni < 4; ni++)
                acc[mi][ni] = __builtin_amdgcn_mfma_f32_16x16x32_bf16(
                    af[mi], bf[ni], acc[mi][ni], 0, 0, 0);
    }

    #pragma unroll
    for (int ni = 0; ni < 4; ni++) {
        const int coln = bn + wn + ni * 16 + cl;
        const int region = coln >> 10, c = coln & 1023;
        const float bs = (region == 0) ? bq[c] : (region == 2) ? bv[c] : 0.f;
        #pragma unroll
        for (int mi = 0; mi < 4; mi++) {
            const int row0 = bm + wm + mi * 16 + quad * 4;
            if (region == 2) {
                const int hh = c >> 6, d = c & 63;
                const int bb = row0 >> 11, s0 = row0 & 2047;
                unsigned short u[4];
                #pragma unroll
                for (int r = 0; r < 4; r++) u[r] = f2bf(acc[mi][ni][r] + bs);
                unsigned short* dst = Cout + (size_t)8 * 1024 * 1024
                    + (((size_t)bb * NH + hh) * HD + d) * S_LEN + s0;
                *(uint2*)dst = *(const uint2*)u;
            } else {
                unsigned short* dst = Cout + (size_t)region * 4 * 1024 * 1024;
                #pragma unroll
                for (int r = 0; r < 4; r++)
                    dst[(size_t)(row0 + r) * 1024 + c] = f2bf(acc[mi][ni][r] + bs);
            }
        }
    }
    (void)M; (void)N;
}

// ---------------------------------------------------------------------------
// MFMA flash attention v3: TQB=64 (grid 1024 = 4 blocks/CU), GLDS-staged
// double-buffered K/V with XOR-swizzled unpadded LDS (40960 B exactly),
// ONE barrier per tile, bias from precomputed global table (off the LDS pipe).
// S^T = mfma(kf, qf): C[key=nb*16+quad*4+r][q=col]; fixed-shift exp2 softmax.
// Swizzle: 16B chunk j at row r lives at slot j^(r&7); all b128 reads and the
// GLDS fill use the same rule (row&7 == col&7 for rows nb*16+col).
// ---------------------------------------------------------------------------
#define TQB 64
#define TKB 64

__global__ __launch_bounds__(256) void attn_mfma(
    const unsigned short* __restrict__ Q, const unsigned short* __restrict__ K,
    const unsigned short* __restrict__ VT, const float* __restrict__ pb_t,
    unsigned short* __restrict__ O)
{
    const int qt = blockIdx.x, h = blockIdx.y, b = blockIdx.z;
    const int tid  = threadIdx.x;
    const int wave = tid >> 6, lane = tid & 63;
    const int quad = lane >> 4, col = lane & 15;
    const int qbase = qt * TQB;
    const int qw = qbase + wave * 16;

    __shared__ __align__(16) unsigned short Ks[2][TKB][HD];   // 16384 B
    __shared__ __align__(16) unsigned short Vs[2][HD][TKB];   // 16384 B
    __shared__ __align__(16) unsigned short Ps[4][16][TKB];   //  8192 B

    bf16x8 qf[2];
    {
        const unsigned short* qp =
            &Q[((size_t)(b * S_LEN) + qw + col) * D_MODEL + h * HD + quad * 8];
        qf[0] = *(const bf16x8*)qp;
        qf[1] = *(const bf16x8*)(qp + 32);
    }

    f32x4 accO[4];
    float lsum = 0.f;
    #pragma unroll
    for (int nb = 0; nb < 4; nb++)
        #pragma unroll
        for (int r = 0; r < 4; r++) accO[nb][r] = 0.f;

    // GLDS staging: 2 instrs each for K and V; slot s=i*256+tid holds
    // (row=s>>3, global chunk (s&7)^(row&7)).
    const int s0 = tid, s1 = 256 + tid;
    const int kr0 = s0 >> 3, kj0 = (s0 & 7) ^ (kr0 & 7);
    const int kr1 = s1 >> 3, kj1 = (s1 & 7) ^ (kr1 & 7);
    const unsigned short* kS0 = K + ((size_t)(b * S_LEN) + kr0) * D_MODEL + h * HD + kj0 * 8;
    const unsigned short* kS1 = K + ((size_t)(b * S_LEN) + kr1) * D_MODEL + h * HD + kj1 * 8;
    const size_t vbase = ((size_t)(b * NH + h) * HD) * S_LEN;
    const unsigned short* vS0 = VT + vbase + (size_t)kr0 * S_LEN + kj0 * 8;
    const unsigned short* vS1 = VT + vbase + (size_t)kr1 * S_LEN + kj1 * 8;

    // stage tile 0 into buffer 0
    {
        unsigned short* kb0 = &Ks[0][0][0] + wave * 512;
        unsigned short* vb0 = &Vs[0][0][0] + wave * 512;
        GLDS(kS0, kb0); GLDS(kS1, kb0 + 2048);
        GLDS(vS0, vb0); GLDS(vS1, vb0 + 2048);
        kS0 += (size_t)TKB * D_MODEL; kS1 += (size_t)TKB * D_MODEL;
        vS0 += TKB; vS1 += TKB;
    }
    __syncthreads();

    const float* pbh = pb_t + h * 4096;
    const int ridx0 = qbase + wave * 16 + col - quad * 4 + 2047;
    const float SC2 = SCORE_SCALE * LOG2E;
    const int jsw = col & 7;   // swizzle key for this lane's rows

    for (int kb = 0, t = 0; kb < S_LEN; kb += TKB, t++) {
        const int p = t & 1;
        // prefetch next tile into the other buffer (drained by end barrier)
        if (kb + TKB < S_LEN) {
            unsigned short* kd = &Ks[p ^ 1][0][0] + wave * 512;
            unsigned short* vd = &Vs[p ^ 1][0][0] + wave * 512;
            GLDS(kS0, kd); GLDS(kS1, kd + 2048);
            GLDS(vS0, vd); GLDS(vS1, vd + 2048);
            kS0 += (size_t)TKB * D_MODEL; kS1 += (size_t)TKB * D_MODEL;
            vS0 += TKB; vS1 += TKB;
        }

        // bias for this tile (L1/L2-hot table; latency covered by QK MFMA)
        float bias_r[16];
        const int rb = ridx0 - kb;
        #pragma unroll
        for (int nb = 0; nb < 4; nb++)
            #pragma unroll
            for (int r = 0; r < 4; r++)
                bias_r[nb * 4 + r] = pbh[rb - nb * 16 - r];

        // QK^T: C[key=nb*16+quad*4+r][q=col]
        f32x4 accS[4];
        #pragma unroll
        for (int nb = 0; nb < 4; nb++)
            #pragma unroll
            for (int r = 0; r < 4; r++) accS[nb][r] = 0.f;
        #pragma unroll
        for (int kk = 0; kk < 2; kk++)
            #pragma unroll
            for (int nb = 0; nb < 4; nb++) {
                const bf16x8 kf = *(const bf16x8*)
                    &Ks[p][nb * 16 + col][((kk * 4 + quad) ^ jsw) * 8];
                accS[nb] = __builtin_amdgcn_mfma_f32_16x16x32_bf16(kf, qf[kk], accS[nb], 0, 0, 0);
            }

        // softmax: p = exp2(score*SC2 + bias2); packed b64 P-writes (swizzled)
        #pragma unroll
        for (int nb = 0; nb < 4; nb++) {
            float pr[4];
            #pragma unroll
            for (int r = 0; r < 4; r++) {
                pr[r] = __builtin_amdgcn_exp2f(fmaf(accS[nb][r], SC2, bias_r[nb * 4 + r]));
                lsum += pr[r];
            }
            const __hip_bfloat162 h0 = __float22bfloat162_rn(make_float2(pr[0], pr[1]));
            const __hip_bfloat162 h1 = __float22bfloat162_rn(make_float2(pr[2], pr[3]));
            uint2 w;
            w.x = *(const unsigned int*)&h0;
            w.y = *(const unsigned int*)&h1;
            const int jp = ((nb * 2 + (quad >> 1)) ^ jsw) * 8 + (quad & 1) * 4;
            *(uint2*)&Ps[wave][col][jp] = w;
        }

        // PV: O[q=quad*4+r][d=nb*16+col] += P[q][key] * V^T[d][key]
        #pragma unroll
        for (int kk = 0; kk < 2; kk++) {
            const bf16x8 af = *(const bf16x8*)
                &Ps[wave][col][((kk * 4 + quad) ^ jsw) * 8];
            #pragma unroll
            for (int nb = 0; nb < 4; nb++) {
                const bf16x8 vf = *(const bf16x8*)
                    &Vs[p][nb * 16 + col][((kk * 4 + quad) ^ jsw) * 8];
                accO[nb] = __builtin_amdgcn_mfma_f32_16x16x32_bf16(af, vf, accO[nb], 0, 0, 0);
            }
        }
        __syncthreads();   // single barrier: readers done + prefetch drained
    }

    // l lives replicated over quads for q=col; reduce, redistribute, store
    lsum += __shfl_xor(lsum, 16);
    lsum += __shfl_xor(lsum, 32);
    #pragma unroll
    for (int r = 0; r < 4; r++) {
        const float inv = 1.0f / __shfl(lsum, quad * 4 + r);
        const size_t row = (size_t)(b * S_LEN) + qw + quad * 4 + r;
        #pragma unroll
        for (int nb = 0; nb < 4; nb++)
            O[row * D_MODEL + h * HD + nb * 16 + col] = f2bf(accO[nb][r] * inv);
    }
}

// ---------------------------------------------------------------------------
// Output projection: out[4096,1024] = Ab @ (Wot_hi + Wot_lo)^T + bo, fp32 out.
// 64x128 tile (512 blocks = 2/CU vs 1/CU before), BK=32, split-precision B.
// ---------------------------------------------------------------------------
#define OBM 64
#define OBN 128

__global__ __launch_bounds__(256) void gemm_out(
    const unsigned short* __restrict__ A, const unsigned short* __restrict__ Bhi,
    const unsigned short* __restrict__ Blo, const float* __restrict__ bias,
    float* __restrict__ Cout)
{
    const int N = 1024, Kd = 1024;
    __shared__ __align__(16) unsigned short As[OBM][GBK];
    __shared__ __align__(16) unsigned short Bs[2][OBN][GBK];

    const int tid = threadIdx.x;
    const int wave = tid >> 6, lane = tid & 63;
    const int quad = lane >> 4, cl = lane & 15;
    const int wm = (wave & 1) * 32, wn = (wave >> 1) * 64;
    const int bm = blockIdx.y * OBM, bn = blockIdx.x * OBN;

    // A: one GLDS (rows tid>>2); B: two each for hi/lo (rows 0..63, 64..127)
    const int ar = tid >> 2, ac = (tid & 3) * 8;
    const unsigned short* aS = A + (size_t)(bm + ar) * Kd + ac;
    const unsigned short* hS0 = Bhi + (size_t)(bn + ar) * Kd + ac;
    const unsigned short* hS1 = hS0 + (size_t)64 * Kd;
    const unsigned short* lS0 = Blo + (size_t)(bn + ar) * Kd + ac;
    const unsigned short* lS1 = lS0 + (size_t)64 * Kd;
    unsigned short* aD  = &As[0][0] + wave * 512;
    unsigned short* hD0 = &Bs[0][0][0] + wave * 512;
    unsigned short* hD1 = hD0 + 2048;
    unsigned short* lD0 = &Bs[1][0][0] + wave * 512;
    unsigned short* lD1 = lD0 + 2048;

    f32x4 acc[2][4];
    #pragma unroll
    for (int mi = 0; mi < 2; mi++)
        #pragma unroll
        for (int ni = 0; ni < 4; ni++)
            #pragma unroll
            for (int r = 0; r < 4; r++) acc[mi][ni][r] = 0.f;

    for (int k0 = 0; k0 < Kd; k0 += GBK) {
        __syncthreads();
        GLDS(aS, aD);
        GLDS(hS0, hD0); GLDS(hS1, hD1);
        GLDS(lS0, lD0); GLDS(lS1, lD1);
        aS += GBK; hS0 += GBK; hS1 += GBK; lS0 += GBK; lS1 += GBK;
        __syncthreads();

        bf16x8 af[2], bh[4];
        #pragma unroll
        for (int mi = 0; mi < 2; mi++)
            af[mi] = *(const bf16x8*)&As[wm + mi * 16 + cl][quad * 8];
        #pragma unroll
        for (int ni = 0; ni < 4; ni++)
            bh[ni] = *(const bf16x8*)&Bs[0][wn + ni * 16 + cl][quad * 8];
        #pragma unroll
        for (int mi = 0; mi < 2; mi++)
            #pragma unroll
            for (int ni = 0; ni < 4; ni++)
                acc[mi][ni] = __builtin_amdgcn_mfma_f32_16x16x32_bf16(
                    af[mi], bh[ni], acc[mi][ni], 0, 0, 0);
        #pragma unroll
        for (int ni = 0; ni < 4; ni++)
            bh[ni] = *(const bf16x8*)&Bs[1][wn + ni * 16 + cl][quad * 8];
        #pragma unroll
        for (int mi = 0; mi < 2; mi++)
            #pragma unroll
            for (int ni = 0; ni < 4; ni++)
                acc[mi][ni] = __builtin_amdgcn_mfma_f32_16x16x32_bf16(
                    af[mi], bh[ni], acc[mi][ni], 0, 0, 0);
    }

    #pragma unroll
    for (int ni = 0; ni < 4; ni++) {
        const int coln = bn + wn + ni * 16 + cl;
        const float bs = bias[coln];
        #pragma unroll
        for (int mi = 0; mi < 2; mi++) {
            const int row0 = bm + wm + mi * 16 + quad * 4;
            #pragma unroll
            for (int r = 0; r < 4; r++)
                Cout[(size_t)(row0 + r) * N + coln] = acc[mi][ni][r] + bs;
        }
    }
}

// ---------------------------------------------------------------------------
extern "C" void kernel_launch(void* const* d_in, const int* in_sizes, int n_in,
                              void* d_out, int out_size, void* d_ws, size_t ws_size,
                              hipStream_t stream)
{
    const float* x        = (const float*)d_in[0];
    const float* Wq       = (const float*)d_in[1];
    const float* bq       = (const float*)d_in[2];
    const float* Wk       = (const float*)d_in[3];
    const float* Wv       = (const float*)d_in[4];
    const float* bv       = (const float*)d_in[5];
    const float* Wo       = (const float*)d_in[6];
    const float* bo       = (const float*)d_in[7];
    const float* pos_bias = (const float*)d_in[8];
    float* out = (float*)d_out;

    const size_t ELEMS  = (size_t)BATCH * S_LEN * D_MODEL;  // 4 Mi
    const size_t WELEMS = (size_t)D_MODEL * D_MODEL;        // 1 Mi
    unsigned short* xb     = (unsigned short*)d_ws;
    unsigned short* Wqkvt  = xb + ELEMS;                    // [3072][1024]
    unsigned short* Wot_hi = Wqkvt + 3 * WELEMS;
    unsigned short* Wot_lo = Wot_hi + WELEMS;
    unsigned short* QKV    = Wot_lo + WELEMS;               // Qb | Kb | VTb
    unsigned short* Qb     = QKV;
    unsigned short* Kb     = Qb + ELEMS;
    unsigned short* VTb    = Kb + ELEMS;                    // [B,H,HD,S]
    unsigned short* Ab     = VTb + ELEMS;                   // attn out bf16 [B,S,D]
    float* pb_t            = (float*)(Ab + ELEMS);          // [NH][4096]

    prep<<<6208, 256, 0, stream>>>(x, Wq, Wk, Wv, Wo, pos_bias,
                                   xb, Wqkvt, Wot_hi, Wot_lo, pb_t);

    gemm_qkv<<<dim3(3072 / GBN, 4096 / GBM), 256, 0, stream>>>(
        xb, Wqkvt, bq, bv, QKV);

    attn_mfma<<<dim3(S_LEN / TQB, NH, BATCH), 256, 0, stream>>>(
        Qb, Kb, VTb, pb_t, Ab);

    gemm_out<<<dim3(1024 / OBN, 4096 / OBM), 256, 0, stream>>>(
        Ab, Wot_hi, Wot_lo, bo, out);
}

// Round 8
// 222.148 us; speedup vs baseline: 1.2413x; 1.0070x over previous
//
#include <hip/hip_runtime.h>
#include <hip/hip_bf16.h>
#include <cstddef>
#include <cstdint>

// Problem constants (fixed by reference)
#define BATCH   2
#define S_LEN   2048
#define D_MODEL 1024
#define NH      16
#define HD      64
#define MAXD    1024

// logits = scores*(1/sqrt(64)) + (scores + rel_bias)*64^-0.25
//        = scores*0.47855339 + rel_bias*0.35355339
#define SCORE_SCALE 0.47855339059327373f
#define BIAS_SCALE  0.35355339059327373f
#define FIXM 8.0f
#define LOG2E 1.4426950408889634f

typedef __attribute__((ext_vector_type(8))) short bf16x8;
typedef __attribute__((ext_vector_type(4))) short bf16x4;
typedef __attribute__((ext_vector_type(4))) float f32x4;

#if __has_builtin(__builtin_amdgcn_mfma_f32_16x16x16bf16_1k)
#define USE_1K 1
#else
#define USE_1K 0
#endif

static __device__ __forceinline__ unsigned short f2bf(float f) {
    __hip_bfloat16 h = __float2bfloat16(f);
    return *reinterpret_cast<unsigned short*>(&h);
}
static __device__ __forceinline__ float bf2f(unsigned short u) {
    union { unsigned int i; float f; } c;
    c.i = ((unsigned int)u) << 16;
    return c.f;
}

#define GLDS(gp, lp) __builtin_amdgcn_global_load_lds( \
    (const __attribute__((address_space(1))) void*)(gp), \
    (__attribute__((address_space(3))) void*)(lp), 16, 0, 0)

// ---------------------------------------------------------------------------
// prep: one launch for (a) x fp32->bf16, (b) 4 weight transpose+converts,
// (c) per-head bias table pb_t[h][rel+2047] with clamp/scales/log2e folded.
// ---------------------------------------------------------------------------
__global__ __launch_bounds__(256) void prep(
    const float* __restrict__ x,
    const float* __restrict__ Wq, const float* __restrict__ Wk,
    const float* __restrict__ Wv, const float* __restrict__ Wo,
    const float* __restrict__ pos_bias,
    unsigned short* __restrict__ xb, unsigned short* __restrict__ Wqkvt,
    unsigned short* __restrict__ Wot_hi, unsigned short* __restrict__ Wot_lo,
    float* __restrict__ pb_t)
{
    __shared__ float t[32][33];
    const int bx = blockIdx.x, tid = threadIdx.x;

    if (bx < 2048) {                       // ---- x convert
        const size_t i = ((size_t)bx * 256 + tid) * 8;
        const float4 a = *(const float4*)(x + i);
        const float4 b = *(const float4*)(x + i + 4);
        unsigned short u[8] = {f2bf(a.x), f2bf(a.y), f2bf(a.z), f2bf(a.w),
                               f2bf(b.x), f2bf(b.y), f2bf(b.z), f2bf(b.w)};
        *(uint4*)(xb + i) = *(const uint4*)u;
    } else if (bx < 6144) {                // ---- weight transpose+convert
        const int bx2 = bx - 2048;
        const int z = bx2 >> 10, inner = bx2 & 1023;
        const int gx = inner & 31, gy = inner >> 5;
        const float* W = (z == 0) ? Wq : (z == 1) ? Wk : (z == 2) ? Wv : Wo;
        unsigned short* hi = (z < 3) ? Wqkvt + (size_t)z * 1024 * 1024 : Wot_hi;
        unsigned short* lo = (z == 3) ? Wot_lo : nullptr;
        const int bxx = gx * 32, byy = gy * 32;
        const int tx = tid & 31, ty = tid >> 5;
        #pragma unroll
        for (int i = 0; i < 4; i++)
            t[ty + 8 * i][tx] = W[(size_t)(byy + ty + 8 * i) * 1024 + bxx + tx];
        __syncthreads();
        #pragma unroll
        for (int i = 0; i < 4; i++) {
            const float v = t[tx][ty + 8 * i];
            const unsigned short hh = f2bf(v);
            const size_t o = (size_t)(bxx + ty + 8 * i) * 1024 + byy + tx;
            hi[o] = hh;
            if (lo) lo[o] = f2bf(v - bf2f(hh));
        }
    } else {                               // ---- bias table, 16 heads x 4096
        const int o0 = (bx - 6144) * 1024 + tid * 4;
        float v[4];
        #pragma unroll
        for (int j = 0; j < 4; j++) {
            const int o = o0 + j;
            const int hh = o >> 12, ii = o & 4095;
            int rel = ii - 2047;
            rel = min(max(rel, -(MAXD - 1)), MAXD - 1);
            v[j] = (BIAS_SCALE * pos_bias[(size_t)(rel + MAXD - 1) * NH + hh] - FIXM) * LOG2E;
        }
        *(float4*)&pb_t[o0] = *(const float4*)v;
    }
}

// ---------------------------------------------------------------------------
// Fused QKV GEMM: C[4096,3072] = xb @ Wqkvt^T. 128x128 tile, BK=32, m97-style.
// Col region 0->Q [B,S,D] (+bq), 1->K [B,S,D], 2->V^T [B,H,HD,S] (+bv, packed).
// ---------------------------------------------------------------------------
#define GBM 128
#define GBN 128
#define GBK 32

__global__ __launch_bounds__(256) void gemm_qkv(
    const unsigned short* __restrict__ A, const unsigned short* __restrict__ Bt,
    const float* __restrict__ bq, const float* __restrict__ bv,
    unsigned short* __restrict__ Cout)
{
    const int K = 1024;
    __shared__ __align__(16) unsigned short As[GBM][GBK];
    __shared__ __align__(16) unsigned short Bs[GBN][GBK];

    const int tid = threadIdx.x;
    const int wave = tid >> 6, lane = tid & 63;
    const int quad = lane >> 4, cl = lane & 15;
    const int wm = (wave & 1) * 64, wn = (wave >> 1) * 64;
    const int bm = blockIdx.y * GBM, bn = blockIdx.x * GBN;

    const int sr = wave * 32 + (lane >> 2);
    const int sc = (lane & 3) * 8;
    const unsigned short* aS0 = A  + (size_t)(bm + sr) * K + sc;
    const unsigned short* aS1 = aS0 + (size_t)16 * K;
    const unsigned short* bS0 = Bt + (size_t)(bn + sr) * K + sc;
    const unsigned short* bS1 = bS0 + (size_t)16 * K;
    unsigned short* aD0 = &As[wave * 32][0];
    unsigned short* aD1 = &As[wave * 32 + 16][0];
    unsigned short* bD0 = &Bs[wave * 32][0];
    unsigned short* bD1 = &Bs[wave * 32 + 16][0];

    f32x4 acc[4][4];
    #pragma unroll
    for (int mi = 0; mi < 4; mi++)
        #pragma unroll
        for (int ni = 0; ni < 4; ni++)
            #pragma unroll
            for (int r = 0; r < 4; r++) acc[mi][ni][r] = 0.f;

    for (int k0 = 0; k0 < K; k0 += GBK) {
        __syncthreads();
        GLDS(aS0, aD0); GLDS(aS1, aD1);
        GLDS(bS0, bD0); GLDS(bS1, bD1);
        aS0 += GBK; aS1 += GBK; bS0 += GBK; bS1 += GBK;
        __syncthreads();

        bf16x8 af[4], bf[4];
        #pragma unroll
        for (int mi = 0; mi < 4; mi++)
            af[mi] = *(const bf16x8*)&As[wm + mi * 16 + cl][quad * 8];
        #pragma unroll
        for (int ni = 0; ni < 4; ni++)
            bf[ni] = *(const bf16x8*)&Bs[wn + ni * 16 + cl][quad * 8];
        #pragma unroll
        for (int mi = 0; mi < 4; mi++)
            #pragma unroll
            for (int ni = 0; ni < 4; ni++)
                acc[mi][ni] = __builtin_amdgcn_mfma_f32_16x16x32_bf16(
                    af[mi], bf[ni], acc[mi][ni], 0, 0, 0);
    }

    #pragma unroll
    for (int ni = 0; ni < 4; ni++) {
        const int coln = bn + wn + ni * 16 + cl;
        const int region = coln >> 10, c = coln & 1023;
        const float bs = (region == 0) ? bq[c] : (region == 2) ? bv[c] : 0.f;
        #pragma unroll
        for (int mi = 0; mi < 4; mi++) {
            const int row0 = bm + wm + mi * 16 + quad * 4;
            if (region == 2) {
                const int hh = c >> 6, d = c & 63;
                const int bb = row0 >> 11, s0 = row0 & 2047;
                unsigned short u[4];
                #pragma unroll
                for (int r = 0; r < 4; r++) u[r] = f2bf(acc[mi][ni][r] + bs);
                unsigned short* dst = Cout + (size_t)8 * 1024 * 1024
                    + (((size_t)bb * NH + hh) * HD + d) * S_LEN + s0;
                *(uint2*)dst = *(const uint2*)u;
            } else {
                unsigned short* dst = Cout + (size_t)region * 4 * 1024 * 1024;
                #pragma unroll
                for (int r = 0; r < 4; r++)
                    dst[(size_t)(row0 + r) * 1024 + c] = f2bf(acc[mi][ni][r] + bs);
            }
        }
    }
}

// ---------------------------------------------------------------------------
// MFMA flash attention v4: TQB=64 (grid 1024), GLDS-staged double-buffered K/V
// with XOR-swizzled unpadded LDS (32768 B -> up to 5 blocks/CU).
// QK^T (S^T) as before: mfma_16x16x32(kf, qf) -> C[key=quad*4+r][q=col].
// PV via mfma_f32_16x16x16_bf16 consuming P DIRECTLY FROM REGISTERS:
//   B-layout of 16x16x16 is B[k=quad*4+i][n=col] == S^T C-layout -> no P LDS
//   round-trip at all. A=V^T[d][key] read as swizzled ds_read_b64.
// lsum via ones-A MFMA (sums across quads in-hardware; no shuffles).
// ---------------------------------------------------------------------------
#define TQB 64
#define TKB 64

__global__ __launch_bounds__(256) void attn_mfma(
    const unsigned short* __restrict__ Q, const unsigned short* __restrict__ K,
    const unsigned short* __restrict__ VT, const float* __restrict__ pb_t,
    unsigned short* __restrict__ O)
{
    const int qt = blockIdx.x, h = blockIdx.y, b = blockIdx.z;
    const int tid  = threadIdx.x;
    const int wave = tid >> 6, lane = tid & 63;
    const int quad = lane >> 4, col = lane & 15;
    const int qbase = qt * TQB;
    const int qw = qbase + wave * 16;

    __shared__ __align__(16) unsigned short Ks[2][TKB][HD];   // 16384 B
    __shared__ __align__(16) unsigned short Vs[2][HD][TKB];   // 16384 B
#if !USE_1K
    __shared__ __align__(16) unsigned short Ps[4][16][TKB];
#endif

    bf16x8 qf[2];
    {
        const unsigned short* qp =
            &Q[((size_t)(b * S_LEN) + qw + col) * D_MODEL + h * HD + quad * 8];
        qf[0] = *(const bf16x8*)qp;
        qf[1] = *(const bf16x8*)(qp + 32);
    }

    f32x4 accO[4];
    #pragma unroll
    for (int nb = 0; nb < 4; nb++)
        #pragma unroll
        for (int r = 0; r < 4; r++) accO[nb][r] = 0.f;
#if USE_1K
    f32x4 accL;
    #pragma unroll
    for (int r = 0; r < 4; r++) accL[r] = 0.f;
    const bf16x4 vone = {(short)16256, (short)16256, (short)16256, (short)16256}; // bf16 1.0
#else
    float lsum = 0.f;
#endif

    // GLDS staging: slot s=i*256+tid holds (row=s>>3, chunk (s&7)^(row&7)).
    const int s0 = tid, s1 = 256 + tid;
    const int kr0 = s0 >> 3, kj0 = (s0 & 7) ^ (kr0 & 7);
    const int kr1 = s1 >> 3, kj1 = (s1 & 7) ^ (kr1 & 7);
    const unsigned short* kS0 = K + ((size_t)(b * S_LEN) + kr0) * D_MODEL + h * HD + kj0 * 8;
    const unsigned short* kS1 = K + ((size_t)(b * S_LEN) + kr1) * D_MODEL + h * HD + kj1 * 8;
    const size_t vbase = ((size_t)(b * NH + h) * HD) * S_LEN;
    const unsigned short* vS0 = VT + vbase + (size_t)kr0 * S_LEN + kj0 * 8;
    const unsigned short* vS1 = VT + vbase + (size_t)kr1 * S_LEN + kj1 * 8;

    // stage tile 0 into buffer 0
    {
        unsigned short* kb0 = &Ks[0][0][0] + wave * 512;
        unsigned short* vb0 = &Vs[0][0][0] + wave * 512;
        GLDS(kS0, kb0); GLDS(kS1, kb0 + 2048);
        GLDS(vS0, vb0); GLDS(vS1, vb0 + 2048);
        kS0 += (size_t)TKB * D_MODEL; kS1 += (size_t)TKB * D_MODEL;
        vS0 += TKB; vS1 += TKB;
    }
    __syncthreads();

    const float* pbh = pb_t + h * 4096;
    const float* pb_lane = pbh + (qbase + wave * 16 + col - quad * 4 + 2047);
    const float SC2 = SCORE_SCALE * LOG2E;
    const int jsw = col & 7;   // swizzle key for this lane's rows

    for (int kb = 0, t = 0; kb < S_LEN; kb += TKB, t++) {
        const int p = t & 1;
        // prefetch next tile into the other buffer (drained by end barrier)
        if (kb + TKB < S_LEN) {
            unsigned short* kd = &Ks[p ^ 1][0][0] + wave * 512;
            unsigned short* vd = &Vs[p ^ 1][0][0] + wave * 512;
            GLDS(kS0, kd); GLDS(kS1, kd + 2048);
            GLDS(vS0, vd); GLDS(vS1, vd + 2048);
            kS0 += (size_t)TKB * D_MODEL; kS1 += (size_t)TKB * D_MODEL;
            vS0 += TKB; vS1 += TKB;
        }

        // bias: immediate-offset loads off a per-lane decrementing pointer
        float bias_r[16];
        #pragma unroll
        for (int nb = 0; nb < 4; nb++)
            #pragma unroll
            for (int r = 0; r < 4; r++)
                bias_r[nb * 4 + r] = pb_lane[-(nb * 16 + r)];

        // QK^T: C[key=nb*16+quad*4+r][q=col]
        f32x4 accS[4];
        #pragma unroll
        for (int nb = 0; nb < 4; nb++)
            #pragma unroll
            for (int r = 0; r < 4; r++) accS[nb][r] = 0.f;
        #pragma unroll
        for (int kk = 0; kk < 2; kk++)
            #pragma unroll
            for (int nb = 0; nb < 4; nb++) {
                const bf16x8 kf = *(const bf16x8*)
                    &Ks[p][nb * 16 + col][((kk * 4 + quad) ^ jsw) * 8];
                accS[nb] = __builtin_amdgcn_mfma_f32_16x16x32_bf16(kf, qf[kk], accS[nb], 0, 0, 0);
            }

        // softmax: p = exp2(score*SC2 + bias2); pack into B-operand fragments
#if USE_1K
        bf16x4 pf[4];
#endif
        #pragma unroll
        for (int nb = 0; nb < 4; nb++) {
            float pr[4];
            #pragma unroll
            for (int r = 0; r < 4; r++)
                pr[r] = __builtin_amdgcn_exp2f(fmaf(accS[nb][r], SC2, bias_r[nb * 4 + r]));
            const __hip_bfloat162 h0 = __float22bfloat162_rn(make_float2(pr[0], pr[1]));
            const __hip_bfloat162 h1 = __float22bfloat162_rn(make_float2(pr[2], pr[3]));
            uint2 w;
            w.x = *(const unsigned int*)&h0;
            w.y = *(const unsigned int*)&h1;
#if USE_1K
            union { uint2 u; bf16x4 v; } cv;
            cv.u = w;
            pf[nb] = cv.v;
            // lsum: ones-A MFMA sums pf over k (across quads) -> accL[*][q=col]
            accL = __builtin_amdgcn_mfma_f32_16x16x16bf16_1k(vone, pf[nb], accL, 0, 0, 0);
#else
            #pragma unroll
            for (int r = 0; r < 4; r++) lsum += pr[r];
            const int jp = ((nb * 2 + (quad >> 1)) ^ jsw) * 8 + (quad & 1) * 4;
            *(uint2*)&Ps[wave][col][jp] = w;
#endif
        }

        // PV
#if USE_1K
        // O^T[d=nb*16+quad*4+r][q=col] += V^T[d][key] * P^T[key][q]
        #pragma unroll
        for (int s = 0; s < 4; s++) {
            #pragma unroll
            for (int nb = 0; nb < 4; nb++) {
                const bf16x4 vf = *(const bf16x4*)
                    &Vs[p][nb * 16 + col][(((2 * s + (quad >> 1)) ^ jsw) * 8) + (quad & 1) * 4];
                accO[nb] = __builtin_amdgcn_mfma_f32_16x16x16bf16_1k(vf, pf[s], accO[nb], 0, 0, 0);
            }
        }
#else
        #pragma unroll
        for (int kk = 0; kk < 2; kk++) {
            const bf16x8 af = *(const bf16x8*)
                &Ps[wave][col][((kk * 4 + quad) ^ jsw) * 8];
            #pragma unroll
            for (int nb = 0; nb < 4; nb++) {
                const bf16x8 vf = *(const bf16x8*)
                    &Vs[p][nb * 16 + col][((kk * 4 + quad) ^ jsw) * 8];
                accO[nb] = __builtin_amdgcn_mfma_f32_16x16x32_bf16(af, vf, accO[nb], 0, 0, 0);
            }
        }
#endif
        pb_lane -= TKB;
        __syncthreads();   // readers done + prefetch drained
    }

#if USE_1K
    // accL rows are all identical = full l for q=col (summed across quads by MFMA)
    const float inv = 1.0f / accL[0];
    const size_t row = (size_t)(b * S_LEN) + qw + col;
    #pragma unroll
    for (int nb = 0; nb < 4; nb++) {
        unsigned short u[4];
        #pragma unroll
        for (int r = 0; r < 4; r++) u[r] = f2bf(accO[nb][r] * inv);
        *(uint2*)&O[row * D_MODEL + h * HD + nb * 16 + quad * 4] = *(const uint2*)u;
    }
#else
    lsum += __shfl_xor(lsum, 16);
    lsum += __shfl_xor(lsum, 32);
    #pragma unroll
    for (int r = 0; r < 4; r++) {
        const float inv = 1.0f / __shfl(lsum, quad * 4 + r);
        const size_t row = (size_t)(b * S_LEN) + qw + quad * 4 + r;
        #pragma unroll
        for (int nb = 0; nb < 4; nb++)
            O[row * D_MODEL + h * HD + nb * 16 + col] = f2bf(accO[nb][r] * inv);
    }
#endif
}

// ---------------------------------------------------------------------------
// Output projection: out[4096,1024] = Ab @ (Wot_hi + Wot_lo)^T + bo, fp32 out.
// 64x128 tile (512 blocks), BK=32, split-precision B.
// ---------------------------------------------------------------------------
#define OBM 64
#define OBN 128

__global__ __launch_bounds__(256) void gemm_out(
    const unsigned short* __restrict__ A, const unsigned short* __restrict__ Bhi,
    const unsigned short* __restrict__ Blo, const float* __restrict__ bias,
    float* __restrict__ Cout)
{
    const int N = 1024, Kd = 1024;
    __shared__ __align__(16) unsigned short As[OBM][GBK];
    __shared__ __align__(16) unsigned short Bs[2][OBN][GBK];

    const int tid = threadIdx.x;
    const int wave = tid >> 6, lane = tid & 63;
    const int quad = lane >> 4, cl = lane & 15;
    const int wm = (wave & 1) * 32, wn = (wave >> 1) * 64;
    const int bm = blockIdx.y * OBM, bn = blockIdx.x * OBN;

    const int ar = tid >> 2, ac = (tid & 3) * 8;
    const unsigned short* aS = A + (size_t)(bm + ar) * Kd + ac;
    const unsigned short* hS0 = Bhi + (size_t)(bn + ar) * Kd + ac;
    const unsigned short* hS1 = hS0 + (size_t)64 * Kd;
    const unsigned short* lS0 = Blo + (size_t)(bn + ar) * Kd + ac;
    const unsigned short* lS1 = lS0 + (size_t)64 * Kd;
    unsigned short* aD  = &As[0][0] + wave * 512;
    unsigned short* hD0 = &Bs[0][0][0] + wave * 512;
    unsigned short* hD1 = hD0 + 2048;
    unsigned short* lD0 = &Bs[1][0][0] + wave * 512;
    unsigned short* lD1 = lD0 + 2048;

    f32x4 acc[2][4];
    #pragma unroll
    for (int mi = 0; mi < 2; mi++)
        #pragma unroll
        for (int ni = 0; ni < 4; ni++)
            #pragma unroll
            for (int r = 0; r < 4; r++) acc[mi][ni][r] = 0.f;

    for (int k0 = 0; k0 < Kd; k0 += GBK) {
        __syncthreads();
        GLDS(aS, aD);
        GLDS(hS0, hD0); GLDS(hS1, hD1);
        GLDS(lS0, lD0); GLDS(lS1, lD1);
        aS += GBK; hS0 += GBK; hS1 += GBK; lS0 += GBK; lS1 += GBK;
        __syncthreads();

        bf16x8 af[2], bh[4];
        #pragma unroll
        for (int mi = 0; mi < 2; mi++)
            af[mi] = *(const bf16x8*)&As[wm + mi * 16 + cl][quad * 8];
        #pragma unroll
        for (int ni = 0; ni < 4; ni++)
            bh[ni] = *(const bf16x8*)&Bs[0][wn + ni * 16 + cl][quad * 8];
        #pragma unroll
        for (int mi = 0; mi < 2; mi++)
            #pragma unroll
            for (int ni = 0; ni < 4; ni++)
                acc[mi][ni] = __builtin_amdgcn_mfma_f32_16x16x32_bf16(
                    af[mi], bh[ni], acc[mi][ni], 0, 0, 0);
        #pragma unroll
        for (int ni = 0; ni < 4; ni++)
            bh[ni] = *(const bf16x8*)&Bs[1][wn + ni * 16 + cl][quad * 8];
        #pragma unroll
        for (int mi = 0; mi < 2; mi++)
            #pragma unroll
            for (int ni = 0; ni < 4; ni++)
                acc[mi][ni] = __builtin_amdgcn_mfma_f32_16x16x32_bf16(
                    af[mi], bh[ni], acc[mi][ni], 0, 0, 0);
    }

    #pragma unroll
    for (int ni = 0; ni < 4; ni++) {
        const int coln = bn + wn + ni * 16 + cl;
        const float bs = bias[coln];
        #pragma unroll
        for (int mi = 0; mi < 2; mi++) {
            const int row0 = bm + wm + mi * 16 + quad * 4;
            #pragma unroll
            for (int r = 0; r < 4; r++)
                Cout[(size_t)(row0 + r) * N + coln] = acc[mi][ni][r] + bs;
        }
    }
}

// ---------------------------------------------------------------------------
extern "C" void kernel_launch(void* const* d_in, const int* in_sizes, int n_in,
                              void* d_out, int out_size, void* d_ws, size_t ws_size,
                              hipStream_t stream)
{
    const float* x        = (const float*)d_in[0];
    const float* Wq       = (const float*)d_in[1];
    const float* bq       = (const float*)d_in[2];
    const float* Wk       = (const float*)d_in[3];
    const float* Wv       = (const float*)d_in[4];
    const float* bv       = (const float*)d_in[5];
    const float* Wo       = (const float*)d_in[6];
    const float* bo       = (const float*)d_in[7];
    const float* pos_bias = (const float*)d_in[8];
    float* out = (float*)d_out;

    const size_t ELEMS  = (size_t)BATCH * S_LEN * D_MODEL;  // 4 Mi
    const size_t WELEMS = (size_t)D_MODEL * D_MODEL;        // 1 Mi
    unsigned short* xb     = (unsigned short*)d_ws;
    unsigned short* Wqkvt  = xb + ELEMS;                    // [3072][1024]
    unsigned short* Wot_hi = Wqkvt + 3 * WELEMS;
    unsigned short* Wot_lo = Wot_hi + WELEMS;
    unsigned short* QKV    = Wot_lo + WELEMS;               // Qb | Kb | VTb
    unsigned short* Qb     = QKV;
    unsigned short* Kb     = Qb + ELEMS;
    unsigned short* VTb    = Kb + ELEMS;                    // [B,H,HD,S]
    unsigned short* Ab     = VTb + ELEMS;                   // attn out bf16 [B,S,D]
    float* pb_t            = (float*)(Ab + ELEMS);          // [NH][4096]

    prep<<<6208, 256, 0, stream>>>(x, Wq, Wk, Wv, Wo, pos_bias,
                                   xb, Wqkvt, Wot_hi, Wot_lo, pb_t);

    gemm_qkv<<<dim3(3072 / GBN, 4096 / GBM), 256, 0, stream>>>(
        xb, Wqkvt, bq, bv, QKV);

    attn_mfma<<<dim3(S_LEN / TQB, NH, BATCH), 256, 0, stream>>>(
        Qb, Kb, VTb, pb_t, Ab);

    gemm_out<<<dim3(1024 / OBN, 4096 / OBM), 256, 0, stream>>>(
        Ab, Wot_hi, Wot_lo, bo, out);
}

// Round 10
// 206.098 us; speedup vs baseline: 1.3379x; 1.0779x over previous
//
#include <hip/hip_runtime.h>
#include <hip/hip_bf16.h>
#include <cstddef>
#include <cstdint>

// Problem constants (fixed by reference)
#define BATCH   2
#define S_LEN   2048
#define D_MODEL 1024
#define NH      16
#define HD      64
#define MAXD    1024

// logits = scores*(1/sqrt(64)) + (scores + rel_bias)*64^-0.25
//        = scores*0.47855339 + rel_bias*0.35355339
#define SCORE_SCALE 0.47855339059327373f
#define BIAS_SCALE  0.35355339059327373f
#define FIXM 8.0f
#define LOG2E 1.4426950408889634f

typedef __attribute__((ext_vector_type(8))) short bf16x8;
typedef __attribute__((ext_vector_type(4))) short bf16x4;
typedef __attribute__((ext_vector_type(4))) float f32x4;

#if __has_builtin(__builtin_amdgcn_mfma_f32_16x16x16bf16_1k)
#define USE_1K 1
#else
#define USE_1K 0
#endif

static __device__ __forceinline__ unsigned short f2bf(float f) {
    __hip_bfloat16 h = __float2bfloat16(f);
    return *reinterpret_cast<unsigned short*>(&h);
}
static __device__ __forceinline__ float bf2f(unsigned short u) {
    union { unsigned int i; float f; } c;
    c.i = ((unsigned int)u) << 16;
    return c.f;
}

#define GLDS(gp, lp) __builtin_amdgcn_global_load_lds( \
    (const __attribute__((address_space(1))) void*)(gp), \
    (__attribute__((address_space(3))) void*)(lp), 16, 0, 0)

// ---------------------------------------------------------------------------
// prep: one launch for (a) x fp32->bf16, (b) 4 weight transpose+converts,
// (c) per-head bias table pb_t[h][rel+2047] with clamp/scales/log2e folded.
// ---------------------------------------------------------------------------
__global__ __launch_bounds__(256) void prep(
    const float* __restrict__ x,
    const float* __restrict__ Wq, const float* __restrict__ Wk,
    const float* __restrict__ Wv, const float* __restrict__ Wo,
    const float* __restrict__ pos_bias,
    unsigned short* __restrict__ xb, unsigned short* __restrict__ Wqkvt,
    unsigned short* __restrict__ Wot,
    float* __restrict__ pb_t)
{
    __shared__ float t[32][33];
    const int bx = blockIdx.x, tid = threadIdx.x;

    if (bx < 2048) {                       // ---- x convert
        const size_t i = ((size_t)bx * 256 + tid) * 8;
        const float4 a = *(const float4*)(x + i);
        const float4 b = *(const float4*)(x + i + 4);
        unsigned short u[8] = {f2bf(a.x), f2bf(a.y), f2bf(a.z), f2bf(a.w),
                               f2bf(b.x), f2bf(b.y), f2bf(b.z), f2bf(b.w)};
        *(uint4*)(xb + i) = *(const uint4*)u;
    } else if (bx < 6144) {                // ---- weight transpose+convert
        const int bx2 = bx - 2048;
        const int z = bx2 >> 10, inner = bx2 & 1023;
        const int gx = inner & 31, gy = inner >> 5;
        const float* W = (z == 0) ? Wq : (z == 1) ? Wk : (z == 2) ? Wv : Wo;
        unsigned short* hi = (z < 3) ? Wqkvt + (size_t)z * 1024 * 1024 : Wot;
        const int bxx = gx * 32, byy = gy * 32;
        const int tx = tid & 31, ty = tid >> 5;
        #pragma unroll
        for (int i = 0; i < 4; i++)
            t[ty + 8 * i][tx] = W[(size_t)(byy + ty + 8 * i) * 1024 + bxx + tx];
        __syncthreads();
        #pragma unroll
        for (int i = 0; i < 4; i++) {
            const float v = t[tx][ty + 8 * i];
            const size_t o = (size_t)(bxx + ty + 8 * i) * 1024 + byy + tx;
            hi[o] = f2bf(v);
        }
    } else {                               // ---- bias table, 16 heads x 4096
        const int o0 = (bx - 6144) * 1024 + tid * 4;
        float v[4];
        #pragma unroll
        for (int j = 0; j < 4; j++) {
            const int o = o0 + j;
            const int hh = o >> 12, ii = o & 4095;
            int rel = ii - 2047;
            rel = min(max(rel, -(MAXD - 1)), MAXD - 1);
            v[j] = (BIAS_SCALE * pos_bias[(size_t)(rel + MAXD - 1) * NH + hh] - FIXM) * LOG2E;
        }
        *(float4*)&pb_t[o0] = *(const float4*)v;
    }
}

// ---------------------------------------------------------------------------
// Fused QKV GEMM: C[4096,3072] = xb @ Wqkvt^T. 128x128 tile, BK=32, m97-style.
// Col region 0->Q [B,S,D] (+bq), 1->K [B,S,D], 2->V^T [B,H,HD,S] (+bv, packed).
// ---------------------------------------------------------------------------
#define GBM 128
#define GBN 128
#define GBK 32

__global__ __launch_bounds__(256) void gemm_qkv(
    const unsigned short* __restrict__ A, const unsigned short* __restrict__ Bt,
    const float* __restrict__ bq, const float* __restrict__ bv,
    unsigned short* __restrict__ Cout)
{
    const int K = 1024;
    __shared__ __align__(16) unsigned short As[GBM][GBK];
    __shared__ __align__(16) unsigned short Bs[GBN][GBK];

    const int tid = threadIdx.x;
    const int wave = tid >> 6, lane = tid & 63;
    const int quad = lane >> 4, cl = lane & 15;
    const int wm = (wave & 1) * 64, wn = (wave >> 1) * 64;
    const int bm = blockIdx.y * GBM, bn = blockIdx.x * GBN;

    const int sr = wave * 32 + (lane >> 2);
    const int sc = (lane & 3) * 8;
    const unsigned short* aS0 = A  + (size_t)(bm + sr) * K + sc;
    const unsigned short* aS1 = aS0 + (size_t)16 * K;
    const unsigned short* bS0 = Bt + (size_t)(bn + sr) * K + sc;
    const unsigned short* bS1 = bS0 + (size_t)16 * K;
    unsigned short* aD0 = &As[wave * 32][0];
    unsigned short* aD1 = &As[wave * 32 + 16][0];
    unsigned short* bD0 = &Bs[wave * 32][0];
    unsigned short* bD1 = &Bs[wave * 32 + 16][0];

    f32x4 acc[4][4];
    #pragma unroll
    for (int mi = 0; mi < 4; mi++)
        #pragma unroll
        for (int ni = 0; ni < 4; ni++)
            #pragma unroll
            for (int r = 0; r < 4; r++) acc[mi][ni][r] = 0.f;

    for (int k0 = 0; k0 < K; k0 += GBK) {
        __syncthreads();
        GLDS(aS0, aD0); GLDS(aS1, aD1);
        GLDS(bS0, bD0); GLDS(bS1, bD1);
        aS0 += GBK; aS1 += GBK; bS0 += GBK; bS1 += GBK;
        __syncthreads();

        bf16x8 af[4], bf[4];
        #pragma unroll
        for (int mi = 0; mi < 4; mi++)
            af[mi] = *(const bf16x8*)&As[wm + mi * 16 + cl][quad * 8];
        #pragma unroll
        for (int ni = 0; ni < 4; ni++)
            bf[ni] = *(const bf16x8*)&Bs[wn + ni * 16 + cl][quad * 8];
        #pragma unroll
        for (int mi = 0; mi < 4; mi++)
            #pragma unroll
            for (int ni = 0; ni < 4; ni++)
                acc[mi][ni] = __builtin_amdgcn_mfma_f32_16x16x32_bf16(
                    af[mi], bf[ni], acc[mi][ni], 0, 0, 0);
    }

    #pragma unroll
    for (int ni = 0; ni < 4; ni++) {
        const int coln = bn + wn + ni * 16 + cl;
        const int region = coln >> 10, c = coln & 1023;
        const float bs = (region == 0) ? bq[c] : (region == 2) ? bv[c] : 0.f;
        #pragma unroll
        for (int mi = 0; mi < 4; mi++) {
            const int row0 = bm + wm + mi * 16 + quad * 4;
            if (region == 2) {
                const int hh = c >> 6, d = c & 63;
                const int bb = row0 >> 11, s0 = row0 & 2047;
                unsigned short u[4];
                #pragma unroll
                for (int r = 0; r < 4; r++) u[r] = f2bf(acc[mi][ni][r] + bs);
                unsigned short* dst = Cout + (size_t)8 * 1024 * 1024
                    + (((size_t)bb * NH + hh) * HD + d) * S_LEN + s0;
                *(uint2*)dst = *(const uint2*)u;
            } else {
                unsigned short* dst = Cout + (size_t)region * 4 * 1024 * 1024;
                #pragma unroll
                for (int r = 0; r < 4; r++)
                    dst[(size_t)(row0 + r) * 1024 + c] = f2bf(acc[mi][ni][r] + bs);
            }
        }
    }
}

// ---------------------------------------------------------------------------
// MFMA flash attention v5: TQB=64, SINGLE-buffer GLDS staging with the proven
// m97 2-barrier pattern (barrier -> GLDS current tile -> barrier -> compute).
// LDS = 16384 B -> 8 blocks/CU (wave cap); extra TLP hides staging latency.
// XOR-swizzled unpadded LDS; register-resident P via mfma_16x16x16 PV;
// lsum via ones-A MFMA; bias from precomputed global table.
// ---------------------------------------------------------------------------
#define TQB 64
#define TKB 64

__global__ __launch_bounds__(256) void attn_mfma(
    const unsigned short* __restrict__ Q, const unsigned short* __restrict__ K,
    const unsigned short* __restrict__ VT, const float* __restrict__ pb_t,
    unsigned short* __restrict__ O)
{
    const int qt = blockIdx.x, h = blockIdx.y, b = blockIdx.z;
    const int tid  = threadIdx.x;
    const int wave = tid >> 6, lane = tid & 63;
    const int quad = lane >> 4, col = lane & 15;
    const int qbase = qt * TQB;
    const int qw = qbase + wave * 16;

    __shared__ __align__(16) unsigned short Ks[TKB][HD];   // 8192 B
    __shared__ __align__(16) unsigned short Vs[HD][TKB];   // 8192 B
#if !USE_1K
    __shared__ __align__(16) unsigned short Ps[4][16][TKB];
#endif

    bf16x8 qf[2];
    {
        const unsigned short* qp =
            &Q[((size_t)(b * S_LEN) + qw + col) * D_MODEL + h * HD + quad * 8];
        qf[0] = *(const bf16x8*)qp;
        qf[1] = *(const bf16x8*)(qp + 32);
    }

    f32x4 accO[4];
    #pragma unroll
    for (int nb = 0; nb < 4; nb++)
        #pragma unroll
        for (int r = 0; r < 4; r++) accO[nb][r] = 0.f;
#if USE_1K
    f32x4 accL;
    #pragma unroll
    for (int r = 0; r < 4; r++) accL[r] = 0.f;
    const bf16x4 vone = {(short)16256, (short)16256, (short)16256, (short)16256}; // bf16 1.0
#else
    float lsum = 0.f;
#endif

    // GLDS staging: slot s=i*256+tid holds (row=s>>3, chunk (s&7)^(row&7)).
    const int s0 = tid, s1 = 256 + tid;
    const int kr0 = s0 >> 3, kj0 = (s0 & 7) ^ (kr0 & 7);
    const int kr1 = s1 >> 3, kj1 = (s1 & 7) ^ (kr1 & 7);
    const unsigned short* kS0 = K + ((size_t)(b * S_LEN) + kr0) * D_MODEL + h * HD + kj0 * 8;
    const unsigned short* kS1 = K + ((size_t)(b * S_LEN) + kr1) * D_MODEL + h * HD + kj1 * 8;
    const size_t vbase = ((size_t)(b * NH + h) * HD) * S_LEN;
    const unsigned short* vS0 = VT + vbase + (size_t)kr0 * S_LEN + kj0 * 8;
    const unsigned short* vS1 = VT + vbase + (size_t)kr1 * S_LEN + kj1 * 8;
    unsigned short* kD = &Ks[0][0] + wave * 512;   // wave-uniform LDS bases
    unsigned short* vD = &Vs[0][0] + wave * 512;

    const float* pbh = pb_t + h * 4096;
    const float* pb_lane = pbh + (qbase + wave * 16 + col - quad * 4 + 2047);
    const float SC2 = SCORE_SCALE * LOG2E;
    const int jsw = col & 7;   // swizzle key for this lane's rows

    for (int kb = 0; kb < S_LEN; kb += TKB) {
        __syncthreads();   // prior tile's LDS reads complete before overwrite
        GLDS(kS0, kD); GLDS(kS1, kD + 2048);
        GLDS(vS0, vD); GLDS(vS1, vD + 2048);
        kS0 += (size_t)TKB * D_MODEL; kS1 += (size_t)TKB * D_MODEL;
        vS0 += TKB; vS1 += TKB;

        // bias loads overlap the GLDS drain (global, off the LDS pipe)
        float bias_r[16];
        #pragma unroll
        for (int nb = 0; nb < 4; nb++)
            #pragma unroll
            for (int r = 0; r < 4; r++)
                bias_r[nb * 4 + r] = pb_lane[-(nb * 16 + r)];

        __syncthreads();   // barrier drains vmcnt -> glds data visible

        // QK^T: C[key=nb*16+quad*4+r][q=col]
        f32x4 accS[4];
        #pragma unroll
        for (int nb = 0; nb < 4; nb++)
            #pragma unroll
            for (int r = 0; r < 4; r++) accS[nb][r] = 0.f;
        #pragma unroll
        for (int kk = 0; kk < 2; kk++)
            #pragma unroll
            for (int nb = 0; nb < 4; nb++) {
                const bf16x8 kf = *(const bf16x8*)
                    &Ks[nb * 16 + col][((kk * 4 + quad) ^ jsw) * 8];
                accS[nb] = __builtin_amdgcn_mfma_f32_16x16x32_bf16(kf, qf[kk], accS[nb], 0, 0, 0);
            }

        // softmax: p = exp2(score*SC2 + bias2); pack into B-operand fragments
#if USE_1K
        bf16x4 pf[4];
#endif
        #pragma unroll
        for (int nb = 0; nb < 4; nb++) {
            float pr[4];
            #pragma unroll
            for (int r = 0; r < 4; r++)
                pr[r] = __builtin_amdgcn_exp2f(fmaf(accS[nb][r], SC2, bias_r[nb * 4 + r]));
            const __hip_bfloat162 h0 = __float22bfloat162_rn(make_float2(pr[0], pr[1]));
            const __hip_bfloat162 h1 = __float22bfloat162_rn(make_float2(pr[2], pr[3]));
            uint2 w;
            w.x = *(const unsigned int*)&h0;
            w.y = *(const unsigned int*)&h1;
#if USE_1K
            union { uint2 u; bf16x4 v; } cv;
            cv.u = w;
            pf[nb] = cv.v;
            // lsum: ones-A MFMA sums pf over k (across quads) -> accL[*][q=col]
            accL = __builtin_amdgcn_mfma_f32_16x16x16bf16_1k(vone, pf[nb], accL, 0, 0, 0);
#else
            #pragma unroll
            for (int r = 0; r < 4; r++) lsum += pr[r];
            const int jp = ((nb * 2 + (quad >> 1)) ^ jsw) * 8 + (quad & 1) * 4;
            *(uint2*)&Ps[wave][col][jp] = w;
#endif
        }

        // PV
#if USE_1K
        // O^T[d=nb*16+quad*4+r][q=col] += V^T[d][key] * P^T[key][q]
        #pragma unroll
        for (int s = 0; s < 4; s++) {
            #pragma unroll
            for (int nb = 0; nb < 4; nb++) {
                const bf16x4 vf = *(const bf16x4*)
                    &Vs[nb * 16 + col][(((2 * s + (quad >> 1)) ^ jsw) * 8) + (quad & 1) * 4];
                accO[nb] = __builtin_amdgcn_mfma_f32_16x16x16bf16_1k(vf, pf[s], accO[nb], 0, 0, 0);
            }
        }
#else
        #pragma unroll
        for (int kk = 0; kk < 2; kk++) {
            const bf16x8 af = *(const bf16x8*)
                &Ps[wave][col][((kk * 4 + quad) ^ jsw) * 8];
            #pragma unroll
            for (int nb = 0; nb < 4; nb++) {
                const bf16x8 vf = *(const bf16x8*)
                    &Vs[nb * 16 + col][((kk * 4 + quad) ^ jsw) * 8];
                accO[nb] = __builtin_amdgcn_mfma_f32_16x16x32_bf16(af, vf, accO[nb], 0, 0, 0);
            }
        }
#endif
        pb_lane -= TKB;
    }

#if USE_1K
    // accL rows are all identical = full l for q=col (summed across quads by MFMA)
    const float inv = 1.0f / accL[0];
    const size_t row = (size_t)(b * S_LEN) + qw + col;
    #pragma unroll
    for (int nb = 0; nb < 4; nb++) {
        unsigned short u[4];
        #pragma unroll
        for (int r = 0; r < 4; r++) u[r] = f2bf(accO[nb][r] * inv);
        *(uint2*)&O[row * D_MODEL + h * HD + nb * 16 + quad * 4] = *(const uint2*)u;
    }
#else
    lsum += __shfl_xor(lsum, 16);
    lsum += __shfl_xor(lsum, 32);
    #pragma unroll
    for (int r = 0; r < 4; r++) {
        const float inv = 1.0f / __shfl(lsum, quad * 4 + r);
        const size_t row = (size_t)(b * S_LEN) + qw + quad * 4 + r;
        #pragma unroll
        for (int nb = 0; nb < 4; nb++)
            O[row * D_MODEL + h * HD + nb * 16 + col] = f2bf(accO[nb][r] * inv);
    }
#endif
}

// ---------------------------------------------------------------------------
// Output projection: out[4096,1024] = Ab @ Wot^T + bo, fp32 out.
// 64x128 tile (512 blocks), BK=32, single bf16 B.
// ---------------------------------------------------------------------------
#define OBM 64
#define OBN 128

__global__ __launch_bounds__(256) void gemm_out(
    const unsigned short* __restrict__ A, const unsigned short* __restrict__ Bt,
    const float* __restrict__ bias, float* __restrict__ Cout)
{
    const int N = 1024, Kd = 1024;
    __shared__ __align__(16) unsigned short As[OBM][GBK];
    __shared__ __align__(16) unsigned short Bs[OBN][GBK];

    const int tid = threadIdx.x;
    const int wave = tid >> 6, lane = tid & 63;
    const int quad = lane >> 4, cl = lane & 15;
    const int wm = (wave & 1) * 32, wn = (wave >> 1) * 64;
    const int bm = blockIdx.y * OBM, bn = blockIdx.x * OBN;

    const int ar = tid >> 2, ac = (tid & 3) * 8;
    const unsigned short* aS = A + (size_t)(bm + ar) * Kd + ac;
    const unsigned short* hS0 = Bt + (size_t)(bn + ar) * Kd + ac;
    const unsigned short* hS1 = hS0 + (size_t)64 * Kd;
    unsigned short* aD  = &As[0][0] + wave * 512;
    unsigned short* hD0 = &Bs[0][0] + wave * 512;
    unsigned short* hD1 = hD0 + 2048;

    f32x4 acc[2][4];
    #pragma unroll
    for (int mi = 0; mi < 2; mi++)
        #pragma unroll
        for (int ni = 0; ni < 4; ni++)
            #pragma unroll
            for (int r = 0; r < 4; r++) acc[mi][ni][r] = 0.f;

    for (int k0 = 0; k0 < Kd; k0 += GBK) {
        __syncthreads();
        GLDS(aS, aD);
        GLDS(hS0, hD0); GLDS(hS1, hD1);
        aS += GBK; hS0 += GBK; hS1 += GBK;
        __syncthreads();

        bf16x8 af[2], bh[4];
        #pragma unroll
        for (int mi = 0; mi < 2; mi++)
            af[mi] = *(const bf16x8*)&As[wm + mi * 16 + cl][quad * 8];
        #pragma unroll
        for (int ni = 0; ni < 4; ni++)
            bh[ni] = *(const bf16x8*)&Bs[wn + ni * 16 + cl][quad * 8];
        #pragma unroll
        for (int mi = 0; mi < 2; mi++)
            #pragma unroll
            for (int ni = 0; ni < 4; ni++)
                acc[mi][ni] = __builtin_amdgcn_mfma_f32_16x16x32_bf16(
                    af[mi], bh[ni], acc[mi][ni], 0, 0, 0);
    }

    #pragma unroll
    for (int ni = 0; ni < 4; ni++) {
        const int coln = bn + wn + ni * 16 + cl;
        const float bs = bias[coln];
        #pragma unroll
        for (int mi = 0; mi < 2; mi++) {
            const int row0 = bm + wm + mi * 16 + quad * 4;
            #pragma unroll
            for (int r = 0; r < 4; r++)
                Cout[(size_t)(row0 + r) * N + coln] = acc[mi][ni][r] + bs;
        }
    }
}

// ---------------------------------------------------------------------------
extern "C" void kernel_launch(void* const* d_in, const int* in_sizes, int n_in,
                              void* d_out, int out_size, void* d_ws, size_t ws_size,
                              hipStream_t stream)
{
    const float* x        = (const float*)d_in[0];
    const float* Wq       = (const float*)d_in[1];
    const float* bq       = (const float*)d_in[2];
    const float* Wk       = (const float*)d_in[3];
    const float* Wv       = (const float*)d_in[4];
    const float* bv       = (const float*)d_in[5];
    const float* Wo       = (const float*)d_in[6];
    const float* bo       = (const float*)d_in[7];
    const float* pos_bias = (const float*)d_in[8];
    float* out = (float*)d_out;

    const size_t ELEMS  = (size_t)BATCH * S_LEN * D_MODEL;  // 4 Mi
    const size_t WELEMS = (size_t)D_MODEL * D_MODEL;        // 1 Mi
    unsigned short* xb     = (unsigned short*)d_ws;
    unsigned short* Wqkvt  = xb + ELEMS;                    // [3072][1024]
    unsigned short* Wot    = Wqkvt + 3 * WELEMS;
    unsigned short* QKV    = Wot + WELEMS;                  // Qb | Kb | VTb
    unsigned short* Qb     = QKV;
    unsigned short* Kb     = Qb + ELEMS;
    unsigned short* VTb    = Kb + ELEMS;                    // [B,H,HD,S]
    unsigned short* Ab     = VTb + ELEMS;                   // attn out bf16 [B,S,D]
    float* pb_t            = (float*)(Ab + ELEMS);          // [NH][4096]

    prep<<<6208, 256, 0, stream>>>(x, Wq, Wk, Wv, Wo, pos_bias,
                                   xb, Wqkvt, Wot, pb_t);

    gemm_qkv<<<dim3(3072 / GBN, 4096 / GBM), 256, 0, stream>>>(
        xb, Wqkvt, bq, bv, QKV);

    attn_mfma<<<dim3(S_LEN / TQB, NH, BATCH), 256, 0, stream>>>(
        Qb, Kb, VTb, pb_t, Ab);

    gemm_out<<<dim3(1024 / OBN, 4096 / OBM), 256, 0, stream>>>(
        Ab, Wot, bo, out);
}